// Round 1
// baseline (606.368 us; speedup 1.0000x reference)
//
#include <hip/hip_runtime.h>

typedef short short8 __attribute__((ext_vector_type(8)));
typedef float f32x4 __attribute__((ext_vector_type(4)));

__device__ __forceinline__ unsigned short f2bf(float f) {
  unsigned int u = __builtin_bit_cast(unsigned int, f);
  u += 0x7fffu + ((u >> 16) & 1u);   // round-to-nearest-even
  return (unsigned short)(u >> 16);
}

// ---- prep: transpose w_off [pos][c][18] -> wT [pos][18][c], convert w_out
// [576][128] fp32 -> wbt [128][576] bf16 (B^T for the GEMM).
__global__ __launch_bounds__(256) void prep(const float* __restrict__ w_off,
                                            const float* __restrict__ w_out,
                                            float* __restrict__ wT,
                                            unsigned short* __restrict__ wbt) {
  int i = blockIdx.x * 256 + threadIdx.x;
  if (i < 73728) {  // 576*128
    int k = i >> 7, n = i & 127;
    wbt[n * 576 + k] = f2bf(w_out[i]);
  }
  int t = i - 73728;
  if (t >= 0 && t < 10368) {  // 9*64*18
    int pos = t / 1152, r = t - pos * 1152;
    int c = r / 18, j = r - c * 18;
    wT[(pos * 18 + j) * 64 + c] = w_off[t];
  }
}

// ---- offset conv: fp32 exact. thread = (pixel, j-group of 9). 262144 threads.
__global__ __launch_bounds__(256) void offconv(const float* __restrict__ x,
                                               const float* __restrict__ wT,
                                               const float* __restrict__ b_off,
                                               float* __restrict__ offs) {
  int gid = blockIdx.x * 256 + threadIdx.x;
  int p = gid >> 1, jg = gid & 1;
  int b = p >> 14, hw = p & 16383, h = hw >> 7, w = hw & 127;
  int jbase = jg * 9;
  float acc[9];
#pragma unroll
  for (int jj = 0; jj < 9; ++jj) acc[jj] = b_off[jbase + jj];
#pragma unroll
  for (int kh = 0; kh < 3; ++kh) {
    int hh = h + kh - 1;
    if (hh < 0 || hh > 127) continue;
#pragma unroll
    for (int kw = 0; kw < 3; ++kw) {
      int ww = w + kw - 1;
      if (ww < 0 || ww > 127) continue;
      const float* xp = x + ((size_t)((b * 128 + hh) * 128 + ww)) * 64;
      const float* wp = wT + ((kh * 3 + kw) * 18 + jbase) * 64;
#pragma unroll 2
      for (int c4 = 0; c4 < 16; ++c4) {
        float4 xv = *(const float4*)(xp + c4 * 4);
#pragma unroll
        for (int jj = 0; jj < 9; ++jj) {
          float4 wv = *(const float4*)(wp + jj * 64 + c4 * 4);
          acc[jj] = fmaf(xv.x, wv.x, acc[jj]);
          acc[jj] = fmaf(xv.y, wv.y, acc[jj]);
          acc[jj] = fmaf(xv.z, wv.z, acc[jj]);
          acc[jj] = fmaf(xv.w, wv.w, acc[jj]);
        }
      }
    }
  }
  float* op = offs + (size_t)p * 18 + jbase;
#pragma unroll
  for (int jj = 0; jj < 9; ++jj) op[jj] = acc[jj];
}

// ---- bilinear sampling: one wave per (pixel, tap); lane = channel.
// Writes sampled[(p - p0)*576 + tap*64 + c] as bf16.
__global__ __launch_bounds__(256) void sample(const float* __restrict__ x,
                                              const float* __restrict__ offs,
                                              unsigned short* __restrict__ sampled,
                                              int p0) {
  int task = blockIdx.x * 4 + (threadIdx.x >> 6);
  int lane = threadIdx.x & 63;
  int p = p0 + task / 9;
  int tap = task - (task / 9) * 9;
  int b = p >> 14, hw = p & 16383, h = hw >> 7, w = hw & 127;
  float xo = offs[(size_t)p * 18 + tap * 2];
  float yo = offs[(size_t)p * 18 + tap * 2 + 1];
  float fx = fminf(fmaxf((float)w + xo, 0.f), 127.f);
  float fy = fminf(fmaxf((float)h + yo, 0.f), 127.f);
  float x0 = floorf(fx), y0 = floorf(fy);
  float x1 = fminf(x0 + 1.f, 127.f), y1 = fminf(y0 + 1.f, 127.f);
  float wx1 = x1 - fx, wx0 = fx - x0;
  float wy1 = y1 - fy, wy0 = fy - y0;
  float wa = wx1 * wy1, wb = wx1 * wy0, wc = wx0 * wy1, wd = wx0 * wy0;
  int ix0 = (int)x0, ix1 = (int)x1, iy0 = (int)y0, iy1 = (int)y1;
  const float* xb = x + (size_t)b * (128 * 128 * 64);
  float va = xb[(iy0 * 128 + ix0) * 64 + lane];
  float vb = xb[(iy1 * 128 + ix0) * 64 + lane];
  float vc = xb[(iy0 * 128 + ix1) * 64 + lane];
  float vd = xb[(iy1 * 128 + ix1) * 64 + lane];
  float v = wa * va + wb * vb + wc * vc + wd * vd;
  sampled[(size_t)(p - p0) * 576 + tap * 64 + lane] = f2bf(v);
}

// ---- GEMM: out[M,128] = sampled[M,576](bf16) x wbt[128,576]^T (bf16) + bias.
// 128x128 tile, BK=32, fragment-order LDS (lane-contiguous 16B slots).
__global__ __launch_bounds__(256) void gemm128(const unsigned short* __restrict__ A,
                                               const unsigned short* __restrict__ Bt,
                                               const float* __restrict__ bias,
                                               float* __restrict__ out,
                                               int p0) {
  __shared__ unsigned short lA[4096];  // 128 rows x 32 k, fragment order
  __shared__ unsigned short lB[4096];
  const int tid = threadIdx.x;
  const int mloc = blockIdx.x * 128;       // row offset within this chunk
  const int m0 = p0 + mloc;                // global output row
  const int lane = tid & 63, wv = tid >> 6;
  const int wi = wv >> 1, wj = wv & 1;
  f32x4 acc[4][4] = {};
  const int r1 = tid >> 2, q = tid & 3;
  const int r2 = r1 + 64;
  const int slot1 = ((r1 >> 4) * 64 + (q << 4) + (r1 & 15)) * 8;
  const int slot2 = ((r2 >> 4) * 64 + (q << 4) + (r2 & 15)) * 8;

  for (int kt = 0; kt < 576; kt += 32) {
    const uint4* ga1 = (const uint4*)(A + (size_t)(mloc + r1) * 576 + kt + q * 8);
    const uint4* ga2 = (const uint4*)(A + (size_t)(mloc + r2) * 576 + kt + q * 8);
    const uint4* gb1 = (const uint4*)(Bt + (size_t)r1 * 576 + kt + q * 8);
    const uint4* gb2 = (const uint4*)(Bt + (size_t)r2 * 576 + kt + q * 8);
    *(uint4*)&lA[slot1] = *ga1;
    *(uint4*)&lA[slot2] = *ga2;
    *(uint4*)&lB[slot1] = *gb1;
    *(uint4*)&lB[slot2] = *gb2;
    __syncthreads();
    short8 av[4], bv[4];
#pragma unroll
    for (int it = 0; it < 4; ++it)
      av[it] = *(const short8*)&lA[((wi * 4 + it) * 64 + lane) * 8];
#pragma unroll
    for (int jt = 0; jt < 4; ++jt)
      bv[jt] = *(const short8*)&lB[((wj * 4 + jt) * 64 + lane) * 8];
#pragma unroll
    for (int it = 0; it < 4; ++it)
#pragma unroll
      for (int jt = 0; jt < 4; ++jt)
        acc[it][jt] = __builtin_amdgcn_mfma_f32_16x16x32_bf16(av[it], bv[jt],
                                                              acc[it][jt], 0, 0, 0);
    __syncthreads();
  }
#pragma unroll
  for (int it = 0; it < 4; ++it) {
    int m = m0 + wi * 64 + it * 16 + (lane >> 4) * 4;
#pragma unroll
    for (int jt = 0; jt < 4; ++jt) {
      int n = wj * 64 + jt * 16 + (lane & 15);
      float bn = bias[n];
#pragma unroll
      for (int r = 0; r < 4; ++r)
        out[(size_t)(m + r) * 128 + n] = acc[it][jt][r] + bn;
    }
  }
}

extern "C" void kernel_launch(void* const* d_in, const int* in_sizes, int n_in,
                              void* d_out, int out_size, void* d_ws, size_t ws_size,
                              hipStream_t stream) {
  const float* x = (const float*)d_in[0];
  const float* w_off = (const float*)d_in[1];
  const float* b_off = (const float*)d_in[2];
  const float* w_out = (const float*)d_in[3];
  const float* b_out = (const float*)d_in[4];
  float* out = (float*)d_out;

  char* ws = (char*)d_ws;
  float* offs = (float*)ws;                              // 131072*18*4 = 9,437,184
  float* wT = (float*)(ws + 9437184);                    // 10368*4     =    41,472
  unsigned short* wbt = (unsigned short*)(ws + 9478656); // 73728*2     =   147,456
  unsigned short* sampled = (unsigned short*)(ws + 9626112);

  prep<<<329, 256, 0, stream>>>(w_off, w_out, wT, wbt);
  offconv<<<1024, 256, 0, stream>>>(x, wT, b_off, offs);

  // chunk sample->gemm through whatever workspace remains (stream-serialized,
  // ws_size is constant so the launch sequence is identical every call).
  const int TOTAL_PX = 131072;
  size_t avail = (ws_size > 9626112) ? ws_size - 9626112 : 0;
  long cp = (long)(avail / (576 * 2));
  cp &= ~127L;  // multiple of 128
  if (cp < 128) cp = 128;          // minimal chunk; assumes ws >= ~10 MB
  if (cp > TOTAL_PX) cp = TOTAL_PX;
  int chunk_px = (int)cp;
  for (int pbase = 0; pbase < TOTAL_PX; pbase += chunk_px) {
    int npx = TOTAL_PX - pbase;
    if (npx > chunk_px) npx = chunk_px;
    sample<<<npx * 9 / 4, 256, 0, stream>>>(x, offs, sampled, pbase);
    gemm128<<<npx / 128, 256, 0, stream>>>(sampled, wbt, b_out, out, pbase);
  }
}